// Round 4
// baseline (669.924 us; speedup 1.0000x reference)
//
#include <hip/hip_runtime.h>
#include <hip/hip_bf16.h>
#include <math.h>

#define NN 20000          // nodes
#define NE 320000         // edges (without self loops)
#define ET (NE + NN)      // edges + self loops
#define NG 64             // graphs
#define HEADS 4
#define HID 128
#define OUTC (HEADS * HID)   // 512
#define SLOPE 0.2f
#define NINF (-1e30f)

__device__ __forceinline__ float lrelu(float v) { return v > 0.f ? v : SLOPE * v; }

// ---------------- CSR build ----------------
__global__ void k_hist(const int* __restrict__ ei, int* __restrict__ deg) {
  int e = blockIdx.x * blockDim.x + threadIdx.x;
  if (e >= ET) return;
  int dst = (e < NE) ? ei[NE + e] : (e - NE);
  atomicAdd(&deg[dst], 1);
}

__global__ void k_scan(const int* __restrict__ deg, int* __restrict__ row_start,
                       int* __restrict__ cursor) {
  __shared__ int sums[1024];
  int tid = threadIdx.x;
  const int PER = (NN + 1023) / 1024;   // 20
  int base = tid * PER;
  int local = 0;
  for (int i = 0; i < PER; ++i) { int idx = base + i; if (idx < NN) local += deg[idx]; }
  sums[tid] = local;
  __syncthreads();
  for (int off = 1; off < 1024; off <<= 1) {
    int v = (tid >= off) ? sums[tid - off] : 0;
    __syncthreads();
    sums[tid] += v;
    __syncthreads();
  }
  int run = sums[tid] - local;  // exclusive prefix
  for (int i = 0; i < PER; ++i) {
    int idx = base + i;
    if (idx < NN) { row_start[idx] = run; cursor[idx] = run; run += deg[idx]; }
  }
  if (tid == 1023) row_start[NN] = sums[1023];
}

__global__ void k_scatter(const int* __restrict__ ei, int* __restrict__ cursor,
                          int* __restrict__ csr_src) {
  int e = blockIdx.x * blockDim.x + threadIdx.x;
  if (e >= ET) return;
  int src, dst;
  if (e < NE) { src = ei[e]; dst = ei[NE + e]; }
  else        { src = e - NE; dst = src; }
  int pos = atomicAdd(&cursor[dst], 1);
  csr_src[pos] = src;
}

// ---------------- tiled GEMM: h = x @ W,  x [NN,K], W [K,512] ----------------
template <int K, int BK>
__global__ void k_gemm_t(const float* __restrict__ x, const float* __restrict__ W,
                         float* __restrict__ h) {
  const int BM = 64, BN = 64;
  __shared__ float sAT[BK][BM + 4];
  __shared__ float sB[BK][BN];
  int tid = threadIdx.x;
  int r0 = blockIdx.y * BM;
  int cb = blockIdx.x * BN;
  int tx = tid & 15, ty = tid >> 4;
  int m0 = ty * 4, n0 = tx * 4;
  float acc[4][4] = {};
  for (int k0 = 0; k0 < K; k0 += BK) {
    const int AF4 = BM * BK / 4;
    for (int idx = tid; idx < AF4; idx += 256) {
      int r = idx / (BK / 4);
      int kq = idx % (BK / 4);
      int row = r0 + r;
      float4 v = make_float4(0.f, 0.f, 0.f, 0.f);
      if (row < NN) v = *reinterpret_cast<const float4*>(&x[(size_t)row * K + k0 + kq * 4]);
      sAT[kq * 4 + 0][r] = v.x;
      sAT[kq * 4 + 1][r] = v.y;
      sAT[kq * 4 + 2][r] = v.z;
      sAT[kq * 4 + 3][r] = v.w;
    }
    const int BF4 = BK * BN / 4;
    for (int idx = tid; idx < BF4; idx += 256) {
      int k = idx / 16, nq = idx & 15;
      float4 v = *reinterpret_cast<const float4*>(&W[(size_t)(k0 + k) * OUTC + cb + nq * 4]);
      *reinterpret_cast<float4*>(&sB[k][nq * 4]) = v;
    }
    __syncthreads();
#pragma unroll 4
    for (int kk = 0; kk < BK; ++kk) {
      float4 a = *reinterpret_cast<const float4*>(&sAT[kk][m0]);
      float4 b = *reinterpret_cast<const float4*>(&sB[kk][n0]);
      acc[0][0] += a.x * b.x; acc[0][1] += a.x * b.y; acc[0][2] += a.x * b.z; acc[0][3] += a.x * b.w;
      acc[1][0] += a.y * b.x; acc[1][1] += a.y * b.y; acc[1][2] += a.y * b.z; acc[1][3] += a.y * b.w;
      acc[2][0] += a.z * b.x; acc[2][1] += a.z * b.y; acc[2][2] += a.z * b.z; acc[2][3] += a.z * b.w;
      acc[3][0] += a.w * b.x; acc[3][1] += a.w * b.y; acc[3][2] += a.w * b.z; acc[3][3] += a.w * b.w;
    }
    __syncthreads();
  }
#pragma unroll
  for (int i = 0; i < 4; ++i) {
    int row = r0 + m0 + i;
    if (row < NN) {
      float4 v = make_float4(acc[i][0], acc[i][1], acc[i][2], acc[i][3]);
      *reinterpret_cast<float4*>(&h[(size_t)row * OUTC + cb + n0]) = v;
    }
  }
}

// ---------------- attention logits per node (float4, 128 thr/node) ----------------
__global__ void k_esd(const float* __restrict__ h, const float* __restrict__ as,
                      const float* __restrict__ ad, float* __restrict__ e_src,
                      float* __restrict__ e_dst) {
  int n = blockIdx.x;
  int tid = threadIdx.x;       // 128
  int head = tid >> 5, q = tid & 31;
  float4 hv = *reinterpret_cast<const float4*>(&h[(size_t)n * OUTC + head * HID + q * 4]);
  float4 av = *reinterpret_cast<const float4*>(&as[head * HID + q * 4]);
  float4 dv = *reinterpret_cast<const float4*>(&ad[head * HID + q * 4]);
  float ps = hv.x * av.x + hv.y * av.y + hv.z * av.z + hv.w * av.w;
  float pd = hv.x * dv.x + hv.y * dv.y + hv.z * dv.z + hv.w * dv.w;
#pragma unroll
  for (int off = 1; off < 32; off <<= 1) {
    ps += __shfl_xor(ps, off);
    pd += __shfl_xor(pd, off);
  }
  if (q == 0) { e_src[n * HEADS + head] = ps; e_dst[n * HEADS + head] = pd; }
}

// ---------------- fused edge-softmax + aggregation: ONE WAVE PER NODE ----------------
// Two-pass softmax (global max first), deferred denominator, 8-edge-deep gather.
// POOL=1: layer-3 variant, atomically accumulates per-graph sums instead of xout.
template <int POOL>
__global__ void __launch_bounds__(256) k_agg(
    const float* __restrict__ h, const float* __restrict__ es,
    const float* __restrict__ ed, const int* __restrict__ row_start,
    const int* __restrict__ csr_src, const float* __restrict__ bias,
    float* __restrict__ xout, const int* __restrict__ batch,
    float* __restrict__ gsums) {
  int wid = threadIdx.x >> 6;
  int lane = threadIdx.x & 63;
  int n = blockIdx.x * 4 + wid;
  if (n >= NN) return;                      // wave-uniform; no barriers anywhere
  int start = row_start[n];
  int deg = row_start[n + 1] - start;
  float4 edv = *reinterpret_cast<const float4*>(&ed[(size_t)n * 4]);
  int head = lane >> 4;
  int c0 = lane * 8;

  // ---- pass 1: global per-head max (es-only sweep, L2-hot) ----
  float m0 = NINF, m1 = NINF, m2 = NINF, m3 = NINF;
  for (int k = lane; k < deg; k += 64) {
    int s = csr_src[start + k];
    float4 e4 = *reinterpret_cast<const float4*>(&es[(size_t)s * 4]);
    m0 = fmaxf(m0, lrelu(e4.x + edv.x));
    m1 = fmaxf(m1, lrelu(e4.y + edv.y));
    m2 = fmaxf(m2, lrelu(e4.z + edv.z));
    m3 = fmaxf(m3, lrelu(e4.w + edv.w));
  }
#pragma unroll
  for (int off = 1; off < 64; off <<= 1) {
    m0 = fmaxf(m0, __shfl_xor(m0, off));
    m1 = fmaxf(m1, __shfl_xor(m1, off));
    m2 = fmaxf(m2, __shfl_xor(m2, off));
    m3 = fmaxf(m3, __shfl_xor(m3, off));
  }

  // ---- pass 2: exp numerators (per-lane denom partials) + deep-unrolled gather ----
  float d0 = 0.f, d1 = 0.f, d2 = 0.f, d3 = 0.f;
  float4 accA = make_float4(0.f, 0.f, 0.f, 0.f);
  float4 accB = make_float4(0.f, 0.f, 0.f, 0.f);
  for (int cb = 0; cb < deg; cb += 64) {
    int m = min(64, deg - cb);
    int s = 0;
    float exh = 0.f;
    if (lane < m) {
      s = csr_src[start + cb + lane];
      float4 e4 = *reinterpret_cast<const float4*>(&es[(size_t)s * 4]);
      float ex0 = __expf(lrelu(e4.x + edv.x) - m0);
      float ex1 = __expf(lrelu(e4.y + edv.y) - m1);
      float ex2 = __expf(lrelu(e4.z + edv.z) - m2);
      float ex3 = __expf(lrelu(e4.w + edv.w) - m3);
      d0 += ex0; d1 += ex1; d2 += ex2; d3 += ex3;
      exh = (head == 0) ? ex0 : (head == 1) ? ex1 : (head == 2) ? ex2 : ex3;
    }
    int j = 0;
    for (; j + 8 <= m; j += 8) {
      const float4* pp[8];
      float av[8];
#pragma unroll
      for (int u = 0; u < 8; ++u) {
        int sj = __shfl(s, j + u);
        av[u] = __shfl(exh, j + u);
        pp[u] = reinterpret_cast<const float4*>(&h[(size_t)sj * OUTC + c0]);
      }
      float4 ha[8], hb[8];
#pragma unroll
      for (int u = 0; u < 8; ++u) { ha[u] = pp[u][0]; hb[u] = pp[u][1]; }
#pragma unroll
      for (int u = 0; u < 8; ++u) {
        accA.x += av[u] * ha[u].x; accA.y += av[u] * ha[u].y;
        accA.z += av[u] * ha[u].z; accA.w += av[u] * ha[u].w;
        accB.x += av[u] * hb[u].x; accB.y += av[u] * hb[u].y;
        accB.z += av[u] * hb[u].z; accB.w += av[u] * hb[u].w;
      }
    }
    for (; j < m; ++j) {
      int sj = __shfl(s, j);
      float a = __shfl(exh, j);
      const float4* p = reinterpret_cast<const float4*>(&h[(size_t)sj * OUTC + c0]);
      float4 ha = p[0], hb = p[1];
      accA.x += a * ha.x; accA.y += a * ha.y; accA.z += a * ha.z; accA.w += a * ha.w;
      accB.x += a * hb.x; accB.y += a * hb.y; accB.z += a * hb.z; accB.w += a * hb.w;
    }
  }
  // ---- reduce denominators once ----
#pragma unroll
  for (int off = 1; off < 64; off <<= 1) {
    d0 += __shfl_xor(d0, off);
    d1 += __shfl_xor(d1, off);
    d2 += __shfl_xor(d2, off);
    d3 += __shfl_xor(d3, off);
  }
  float dh = (head == 0) ? d0 : (head == 1) ? d1 : (head == 2) ? d2 : d3;
  float inv = 1.f / dh;
  accA.x *= inv; accA.y *= inv; accA.z *= inv; accA.w *= inv;
  accB.x *= inv; accB.y *= inv; accB.z *= inv; accB.w *= inv;
  // ---- head-sum across lane groups (l^16, l^32) ----
#pragma unroll
  for (int off = 16; off < 64; off <<= 1) {
    accA.x += __shfl_xor(accA.x, off); accA.y += __shfl_xor(accA.y, off);
    accA.z += __shfl_xor(accA.z, off); accA.w += __shfl_xor(accA.w, off);
    accB.x += __shfl_xor(accB.x, off); accB.y += __shfl_xor(accB.y, off);
    accB.z += __shfl_xor(accB.z, off); accB.w += __shfl_xor(accB.w, off);
  }
  if (lane < 16) {
    int cc = lane * 8;
    float4 b0 = *reinterpret_cast<const float4*>(&bias[cc]);
    float4 b1 = *reinterpret_cast<const float4*>(&bias[cc + 4]);
    float4 o0, o1;
    o0.x = fmaxf(accA.x * 0.25f + b0.x, 0.f);
    o0.y = fmaxf(accA.y * 0.25f + b0.y, 0.f);
    o0.z = fmaxf(accA.z * 0.25f + b0.z, 0.f);
    o0.w = fmaxf(accA.w * 0.25f + b0.w, 0.f);
    o1.x = fmaxf(accB.x * 0.25f + b1.x, 0.f);
    o1.y = fmaxf(accB.y * 0.25f + b1.y, 0.f);
    o1.z = fmaxf(accB.z * 0.25f + b1.z, 0.f);
    o1.w = fmaxf(accB.w * 0.25f + b1.w, 0.f);
    if (POOL) {
      int g = batch[n];
      float* gp = &gsums[(size_t)g * HID + cc];
      atomicAdd(&gp[0], o0.x); atomicAdd(&gp[1], o0.y);
      atomicAdd(&gp[2], o0.z); atomicAdd(&gp[3], o0.w);
      atomicAdd(&gp[4], o1.x); atomicAdd(&gp[5], o1.y);
      atomicAdd(&gp[6], o1.z); atomicAdd(&gp[7], o1.w);
    } else {
      *reinterpret_cast<float4*>(&xout[(size_t)n * HID + cc]) = o0;
      *reinterpret_cast<float4*>(&xout[(size_t)n * HID + cc + 4]) = o1;
    }
  }
}

// ---------------- MLP head (counts via binary search over sorted batch) ----------------
__global__ void k_mlp(const float* __restrict__ sums, const int* __restrict__ batch,
                      const float* __restrict__ bst, const float* __restrict__ M1,
                      const float* __restrict__ mb1, const float* __restrict__ M2,
                      const float* __restrict__ mb2, const float* __restrict__ M3,
                      const float* __restrict__ mb3, float* __restrict__ out) {
  int g = blockIdx.x, tid = threadIdx.x;  // 128 threads
  int lo = 0, hi = NN;
  while (lo < hi) { int mid = (lo + hi) >> 1; if (batch[mid] < g) lo = mid + 1; else hi = mid; }
  int s = lo;
  lo = s; hi = NN;
  while (lo < hi) { int mid = (lo + hi) >> 1; if (batch[mid] < g + 1) lo = mid + 1; else hi = mid; }
  int e = lo;
  float cnt = (float)(e - s);
  float pooled = sums[g * HID + tid] / fmaxf(cnt, 1.f);
  __shared__ float z[HID + 1];
  __shared__ float z1[HID];
  __shared__ float z2[64];
  z[tid] = pooled;
  if (tid == 0) z[HID] = log1pf(bst[g]);
  __syncthreads();
  float a1 = mb1[tid];
  for (int k = 0; k < HID + 1; ++k) a1 += z[k] * M1[k * HID + tid];
  z1[tid] = a1 > 0.f ? a1 : 0.f;
  __syncthreads();
  if (tid < 64) {
    float a2 = mb2[tid];
    for (int k = 0; k < HID; ++k) a2 += z1[k] * M2[k * 64 + tid];
    z2[tid] = a2 > 0.f ? a2 : 0.f;
  }
  __syncthreads();
  if (tid < 2) {
    float a3 = mb3[tid];
    for (int k = 0; k < 64; ++k) a3 += z2[k] * M3[k * 2 + tid];
    out[g * 2 + tid] = a3;
  }
}

extern "C" void kernel_launch(void* const* d_in, const int* in_sizes, int n_in,
                              void* d_out, int out_size, void* d_ws, size_t ws_size,
                              hipStream_t stream) {
  const float* x   = (const float*)d_in[0];
  const int*   ei  = (const int*)d_in[1];
  const int*   bat = (const int*)d_in[2];
  const float* bst = (const float*)d_in[3];
  const float* W1 = (const float*)d_in[4];
  const float* as1 = (const float*)d_in[5];
  const float* ad1 = (const float*)d_in[6];
  const float* b1 = (const float*)d_in[7];
  const float* W2 = (const float*)d_in[8];
  const float* as2 = (const float*)d_in[9];
  const float* ad2 = (const float*)d_in[10];
  const float* b2 = (const float*)d_in[11];
  const float* W3 = (const float*)d_in[12];
  const float* as3 = (const float*)d_in[13];
  const float* ad3 = (const float*)d_in[14];
  const float* b3 = (const float*)d_in[15];
  const float* M1 = (const float*)d_in[16];
  const float* mb1 = (const float*)d_in[17];
  const float* M2 = (const float*)d_in[18];
  const float* mb2 = (const float*)d_in[19];
  const float* M3 = (const float*)d_in[20];
  const float* mb3 = (const float*)d_in[21];
  float* out = (float*)d_out;

  char* ws = (char*)d_ws;
  auto alloc = [&](size_t bytes) -> void* {
    void* p = (void*)ws;
    ws += (bytes + 255) & ~(size_t)255;
    return p;
  };
  float* h_buf  = (float*)alloc((size_t)NN * OUTC * 4);
  float* x_buf  = (float*)alloc((size_t)NN * HID * 4);
  float* e_src  = (float*)alloc((size_t)NN * 4 * 4);
  float* e_dst  = (float*)alloc((size_t)NN * 4 * 4);
  int*   deg    = (int*)alloc((size_t)NN * 4);
  int*   rowst  = (int*)alloc((size_t)(NN + 1) * 4);
  int*   cursor = (int*)alloc((size_t)NN * 4);
  int*   csr    = (int*)alloc((size_t)ET * 4);
  float* gsums  = (float*)alloc((size_t)NG * HID * 4);

  // CSR by destination
  hipMemsetAsync(deg, 0, (size_t)NN * 4, stream);
  hipMemsetAsync(gsums, 0, (size_t)NG * HID * 4, stream);
  k_hist<<<(ET + 255) / 256, 256, 0, stream>>>(ei, deg);
  k_scan<<<1, 1024, 0, stream>>>(deg, rowst, cursor);
  k_scatter<<<(ET + 255) / 256, 256, 0, stream>>>(ei, cursor, csr);

  dim3 ggrid(OUTC / 64, (NN + 63) / 64);
  dim3 agrid((NN + 3) / 4);
  // layer 1
  k_gemm_t<12, 12><<<ggrid, 256, 0, stream>>>(x, W1, h_buf);
  k_esd<<<NN, 128, 0, stream>>>(h_buf, as1, ad1, e_src, e_dst);
  k_agg<0><<<agrid, 256, 0, stream>>>(h_buf, e_src, e_dst, rowst, csr, b1, x_buf, bat, gsums);
  // layer 2
  k_gemm_t<128, 64><<<ggrid, 256, 0, stream>>>(x_buf, W2, h_buf);
  k_esd<<<NN, 128, 0, stream>>>(h_buf, as2, ad2, e_src, e_dst);
  k_agg<0><<<agrid, 256, 0, stream>>>(h_buf, e_src, e_dst, rowst, csr, b2, x_buf, bat, gsums);
  // layer 3 (pool fused via atomics into gsums)
  k_gemm_t<128, 64><<<ggrid, 256, 0, stream>>>(x_buf, W3, h_buf);
  k_esd<<<NN, 128, 0, stream>>>(h_buf, as3, ad3, e_src, e_dst);
  k_agg<1><<<agrid, 256, 0, stream>>>(h_buf, e_src, e_dst, rowst, csr, b3, x_buf, bat, gsums);
  // MLP head
  k_mlp<<<NG, 128, 0, stream>>>(gsums, bat, bst, M1, mb1, M2, mb2, M3, mb3, out);
}

// Round 6
// 590.578 us; speedup vs baseline: 1.1344x; 1.1344x over previous
//
#include <hip/hip_runtime.h>
#include <hip/hip_bf16.h>
#include <math.h>

#define NN 20000          // nodes
#define NE 320000         // edges (without self loops)
#define ET (NE + NN)      // edges + self loops
#define NG 64             // graphs
#define HEADS 4
#define HID 128
#define OUTC (HEADS * HID)   // 512
#define SLOPE 0.2f
#define NINF (-1e30f)

__device__ __forceinline__ float lrelu(float v) { return v > 0.f ? v : SLOPE * v; }

// ---------------- CSR build ----------------
__global__ void k_hist(const int* __restrict__ ei, int* __restrict__ deg) {
  int e = blockIdx.x * blockDim.x + threadIdx.x;
  if (e >= ET) return;
  int dst = (e < NE) ? ei[NE + e] : (e - NE);
  atomicAdd(&deg[dst], 1);
}

__global__ void k_scan(const int* __restrict__ deg, int* __restrict__ row_start,
                       int* __restrict__ cursor) {
  __shared__ int sums[1024];
  int tid = threadIdx.x;
  const int PER = (NN + 1023) / 1024;   // 20
  int base = tid * PER;
  int local = 0;
  for (int i = 0; i < PER; ++i) { int idx = base + i; if (idx < NN) local += deg[idx]; }
  sums[tid] = local;
  __syncthreads();
  for (int off = 1; off < 1024; off <<= 1) {
    int v = (tid >= off) ? sums[tid - off] : 0;
    __syncthreads();
    sums[tid] += v;
    __syncthreads();
  }
  int run = sums[tid] - local;  // exclusive prefix
  for (int i = 0; i < PER; ++i) {
    int idx = base + i;
    if (idx < NN) { row_start[idx] = run; cursor[idx] = run; run += deg[idx]; }
  }
  if (tid == 1023) row_start[NN] = sums[1023];
}

__global__ void k_scatter(const int* __restrict__ ei, int* __restrict__ cursor,
                          int* __restrict__ csr_src) {
  int e = blockIdx.x * blockDim.x + threadIdx.x;
  if (e >= ET) return;
  int src, dst;
  if (e < NE) { src = ei[e]; dst = ei[NE + e]; }
  else        { src = e - NE; dst = src; }
  int pos = atomicAdd(&cursor[dst], 1);
  csr_src[pos] = src;
}

// ---------------- tiled GEMM: h = x @ W,  x [NN,K], W [K,512] ----------------
template <int K, int BK>
__global__ void k_gemm_t(const float* __restrict__ x, const float* __restrict__ W,
                         float* __restrict__ h) {
  const int BM = 64, BN = 64;
  __shared__ float sAT[BK][BM + 4];
  __shared__ float sB[BK][BN];
  int tid = threadIdx.x;
  int r0 = blockIdx.y * BM;
  int cb = blockIdx.x * BN;
  int tx = tid & 15, ty = tid >> 4;
  int m0 = ty * 4, n0 = tx * 4;
  float acc[4][4] = {};
  for (int k0 = 0; k0 < K; k0 += BK) {
    const int AF4 = BM * BK / 4;
    for (int idx = tid; idx < AF4; idx += 256) {
      int r = idx / (BK / 4);
      int kq = idx % (BK / 4);
      int row = r0 + r;
      float4 v = make_float4(0.f, 0.f, 0.f, 0.f);
      if (row < NN) v = *reinterpret_cast<const float4*>(&x[(size_t)row * K + k0 + kq * 4]);
      sAT[kq * 4 + 0][r] = v.x;
      sAT[kq * 4 + 1][r] = v.y;
      sAT[kq * 4 + 2][r] = v.z;
      sAT[kq * 4 + 3][r] = v.w;
    }
    const int BF4 = BK * BN / 4;
    for (int idx = tid; idx < BF4; idx += 256) {
      int k = idx / 16, nq = idx & 15;
      float4 v = *reinterpret_cast<const float4*>(&W[(size_t)(k0 + k) * OUTC + cb + nq * 4]);
      *reinterpret_cast<float4*>(&sB[k][nq * 4]) = v;
    }
    __syncthreads();
#pragma unroll 4
    for (int kk = 0; kk < BK; ++kk) {
      float4 a = *reinterpret_cast<const float4*>(&sAT[kk][m0]);
      float4 b = *reinterpret_cast<const float4*>(&sB[kk][n0]);
      acc[0][0] += a.x * b.x; acc[0][1] += a.x * b.y; acc[0][2] += a.x * b.z; acc[0][3] += a.x * b.w;
      acc[1][0] += a.y * b.x; acc[1][1] += a.y * b.y; acc[1][2] += a.y * b.z; acc[1][3] += a.y * b.w;
      acc[2][0] += a.z * b.x; acc[2][1] += a.z * b.y; acc[2][2] += a.z * b.z; acc[2][3] += a.z * b.w;
      acc[3][0] += a.w * b.x; acc[3][1] += a.w * b.y; acc[3][2] += a.w * b.z; acc[3][3] += a.w * b.w;
    }
    __syncthreads();
  }
#pragma unroll
  for (int i = 0; i < 4; ++i) {
    int row = r0 + m0 + i;
    if (row < NN) {
      float4 v = make_float4(acc[i][0], acc[i][1], acc[i][2], acc[i][3]);
      *reinterpret_cast<float4*>(&h[(size_t)row * OUTC + cb + n0]) = v;
    }
  }
}

// ---------------- attention logits per node (float4, 128 thr/node) ----------------
__global__ void k_esd(const float* __restrict__ h, const float* __restrict__ as,
                      const float* __restrict__ ad, float* __restrict__ e_src,
                      float* __restrict__ e_dst) {
  int n = blockIdx.x;
  int tid = threadIdx.x;       // 128
  int head = tid >> 5, q = tid & 31;
  float4 hv = *reinterpret_cast<const float4*>(&h[(size_t)n * OUTC + head * HID + q * 4]);
  float4 av = *reinterpret_cast<const float4*>(&as[head * HID + q * 4]);
  float4 dv = *reinterpret_cast<const float4*>(&ad[head * HID + q * 4]);
  float ps = hv.x * av.x + hv.y * av.y + hv.z * av.z + hv.w * av.w;
  float pd = hv.x * dv.x + hv.y * dv.y + hv.z * dv.z + hv.w * dv.w;
#pragma unroll
  for (int off = 1; off < 32; off <<= 1) {
    ps += __shfl_xor(ps, off);
    pd += __shfl_xor(pd, off);
  }
  if (q == 0) { e_src[n * HEADS + head] = ps; e_dst[n * HEADS + head] = pd; }
}

// ---------------- fused edge-softmax + aggregation: TWO WAVES PER NODE ----------------
// 2 nodes per 256-thread block (grid = NN/2). wave half=0 owns heads {0,1},
// half=1 owns heads {2,3}. Lane owns 4 channels; one float4 load per edge;
// named 8-deep unroll. ALL __shfl are wave-uniform (both head variants
// broadcast unconditionally, select AFTER — bpermute from exec-masked lanes
// is unreliable, that was round 5's bug).
template <int POOL>
__global__ void __launch_bounds__(256) k_agg(
    const float* __restrict__ h, const float* __restrict__ es,
    const float* __restrict__ ed, const int* __restrict__ row_start,
    const int* __restrict__ csr_src, const float* __restrict__ bias,
    float* __restrict__ xout, const int* __restrict__ batch,
    float* __restrict__ gsums) {
  __shared__ float xsum[2][HID];
  int tid = threadIdx.x;
  int wid = tid >> 6;          // 0..3
  int lane = tid & 63;
  int slot = wid >> 1;         // node within block
  int half = wid & 1;          // channel half: heads {2*half, 2*half+1}
  int n = blockIdx.x * 2 + slot;
  int start = row_start[n];
  int deg = row_start[n + 1] - start;
  float2 edv = *reinterpret_cast<const float2*>(&ed[(size_t)n * 4 + half * 2]);
  int cg = half * 256 + lane * 4;   // global channel base (float4-aligned)

  // ---- pass 1: per-head max over incoming edges (this wave's 2 heads) ----
  float mE = NINF, mO = NINF;
  for (int k = lane; k < deg; k += 64) {
    int s = csr_src[start + k];
    float2 e2 = *reinterpret_cast<const float2*>(&es[(size_t)s * 4 + half * 2]);
    mE = fmaxf(mE, lrelu(e2.x + edv.x));
    mO = fmaxf(mO, lrelu(e2.y + edv.y));
  }
#pragma unroll
  for (int off = 1; off < 64; off <<= 1) {
    mE = fmaxf(mE, __shfl_xor(mE, off));
    mO = fmaxf(mO, __shfl_xor(mO, off));
  }

  // ---- pass 2: exp numerators + deep gather ----
  float dE = 0.f, dO = 0.f;
  float4 acc = make_float4(0.f, 0.f, 0.f, 0.f);
  bool evenHead = (lane < 32);
  for (int cb = 0; cb < deg; cb += 64) {
    int m = min(64, deg - cb);
    int s = 0;
    float exE = 0.f, exO = 0.f;
    if (lane < m) {
      s = csr_src[start + cb + lane];
      float2 e2 = *reinterpret_cast<const float2*>(&es[(size_t)s * 4 + half * 2]);
      exE = __expf(lrelu(e2.x + edv.x) - mE);
      exO = __expf(lrelu(e2.y + edv.y) - mO);
      dE += exE;
      dO += exO;
    }
    int j = 0;
    for (; j + 8 <= m; j += 8) {
      int s0 = __shfl(s, j + 0), s1 = __shfl(s, j + 1);
      int s2 = __shfl(s, j + 2), s3 = __shfl(s, j + 3);
      int s4 = __shfl(s, j + 4), s5 = __shfl(s, j + 5);
      int s6 = __shfl(s, j + 6), s7 = __shfl(s, j + 7);
      // uniform broadcasts of BOTH head exps, then per-lane select
      float aE0 = __shfl(exE, j + 0), aO0 = __shfl(exO, j + 0);
      float aE1 = __shfl(exE, j + 1), aO1 = __shfl(exO, j + 1);
      float aE2 = __shfl(exE, j + 2), aO2 = __shfl(exO, j + 2);
      float aE3 = __shfl(exE, j + 3), aO3 = __shfl(exO, j + 3);
      float aE4 = __shfl(exE, j + 4), aO4 = __shfl(exO, j + 4);
      float aE5 = __shfl(exE, j + 5), aO5 = __shfl(exO, j + 5);
      float aE6 = __shfl(exE, j + 6), aO6 = __shfl(exO, j + 6);
      float aE7 = __shfl(exE, j + 7), aO7 = __shfl(exO, j + 7);
      float a0 = evenHead ? aE0 : aO0;
      float a1 = evenHead ? aE1 : aO1;
      float a2 = evenHead ? aE2 : aO2;
      float a3 = evenHead ? aE3 : aO3;
      float a4 = evenHead ? aE4 : aO4;
      float a5 = evenHead ? aE5 : aO5;
      float a6 = evenHead ? aE6 : aO6;
      float a7 = evenHead ? aE7 : aO7;
      float4 h0 = *reinterpret_cast<const float4*>(&h[(size_t)s0 * OUTC + cg]);
      float4 h1 = *reinterpret_cast<const float4*>(&h[(size_t)s1 * OUTC + cg]);
      float4 h2 = *reinterpret_cast<const float4*>(&h[(size_t)s2 * OUTC + cg]);
      float4 h3 = *reinterpret_cast<const float4*>(&h[(size_t)s3 * OUTC + cg]);
      float4 h4 = *reinterpret_cast<const float4*>(&h[(size_t)s4 * OUTC + cg]);
      float4 h5 = *reinterpret_cast<const float4*>(&h[(size_t)s5 * OUTC + cg]);
      float4 h6 = *reinterpret_cast<const float4*>(&h[(size_t)s6 * OUTC + cg]);
      float4 h7 = *reinterpret_cast<const float4*>(&h[(size_t)s7 * OUTC + cg]);
      acc.x += a0 * h0.x; acc.y += a0 * h0.y; acc.z += a0 * h0.z; acc.w += a0 * h0.w;
      acc.x += a1 * h1.x; acc.y += a1 * h1.y; acc.z += a1 * h1.z; acc.w += a1 * h1.w;
      acc.x += a2 * h2.x; acc.y += a2 * h2.y; acc.z += a2 * h2.z; acc.w += a2 * h2.w;
      acc.x += a3 * h3.x; acc.y += a3 * h3.y; acc.z += a3 * h3.z; acc.w += a3 * h3.w;
      acc.x += a4 * h4.x; acc.y += a4 * h4.y; acc.z += a4 * h4.z; acc.w += a4 * h4.w;
      acc.x += a5 * h5.x; acc.y += a5 * h5.y; acc.z += a5 * h5.z; acc.w += a5 * h5.w;
      acc.x += a6 * h6.x; acc.y += a6 * h6.y; acc.z += a6 * h6.z; acc.w += a6 * h6.w;
      acc.x += a7 * h7.x; acc.y += a7 * h7.y; acc.z += a7 * h7.z; acc.w += a7 * h7.w;
    }
    for (; j < m; ++j) {
      int sj = __shfl(s, j);
      float aE = __shfl(exE, j), aO = __shfl(exO, j);
      float a = evenHead ? aE : aO;
      float4 hv = *reinterpret_cast<const float4*>(&h[(size_t)sj * OUTC + cg]);
      acc.x += a * hv.x; acc.y += a * hv.y; acc.z += a * hv.z; acc.w += a * hv.w;
    }
  }
  // ---- reduce denominators once ----
#pragma unroll
  for (int off = 1; off < 64; off <<= 1) {
    dE += __shfl_xor(dE, off);
    dO += __shfl_xor(dO, off);
  }
  float inv = 1.f / (evenHead ? dE : dO);
  acc.x *= inv; acc.y *= inv; acc.z *= inv; acc.w *= inv;
  // ---- sum the wave's two heads: lane l (<32) += lane l+32 (same head-local channel) ----
  acc.x += __shfl_xor(acc.x, 32);
  acc.y += __shfl_xor(acc.y, 32);
  acc.z += __shfl_xor(acc.z, 32);
  acc.w += __shfl_xor(acc.w, 32);
  // ---- cross-wave combine via LDS ----
  if (half == 1 && lane < 32)
    *reinterpret_cast<float4*>(&xsum[slot][lane * 4]) = acc;
  __syncthreads();
  if (half == 0 && lane < 32) {
    float4 other = *reinterpret_cast<const float4*>(&xsum[slot][lane * 4]);
    float4 bv = *reinterpret_cast<const float4*>(&bias[lane * 4]);
    float4 o;
    o.x = fmaxf((acc.x + other.x) * 0.25f + bv.x, 0.f);
    o.y = fmaxf((acc.y + other.y) * 0.25f + bv.y, 0.f);
    o.z = fmaxf((acc.z + other.z) * 0.25f + bv.z, 0.f);
    o.w = fmaxf((acc.w + other.w) * 0.25f + bv.w, 0.f);
    if (POOL) {
      int g = batch[n];
      float* gp = &gsums[(size_t)g * HID + lane * 4];
      atomicAdd(&gp[0], o.x); atomicAdd(&gp[1], o.y);
      atomicAdd(&gp[2], o.z); atomicAdd(&gp[3], o.w);
    } else {
      *reinterpret_cast<float4*>(&xout[(size_t)n * HID + lane * 4]) = o;
    }
  }
}

// ---------------- MLP head (counts via binary search over sorted batch) ----------------
__global__ void k_mlp(const float* __restrict__ sums, const int* __restrict__ batch,
                      const float* __restrict__ bst, const float* __restrict__ M1,
                      const float* __restrict__ mb1, const float* __restrict__ M2,
                      const float* __restrict__ mb2, const float* __restrict__ M3,
                      const float* __restrict__ mb3, float* __restrict__ out) {
  int g = blockIdx.x, tid = threadIdx.x;  // 128 threads
  int lo = 0, hi = NN;
  while (lo < hi) { int mid = (lo + hi) >> 1; if (batch[mid] < g) lo = mid + 1; else hi = mid; }
  int s = lo;
  lo = s; hi = NN;
  while (lo < hi) { int mid = (lo + hi) >> 1; if (batch[mid] < g + 1) lo = mid + 1; else hi = mid; }
  int e = lo;
  float cnt = (float)(e - s);
  float pooled = sums[g * HID + tid] / fmaxf(cnt, 1.f);
  __shared__ float z[HID + 1];
  __shared__ float z1[HID];
  __shared__ float z2[64];
  z[tid] = pooled;
  if (tid == 0) z[HID] = log1pf(bst[g]);
  __syncthreads();
  float a1 = mb1[tid];
  for (int k = 0; k < HID + 1; ++k) a1 += z[k] * M1[k * HID + tid];
  z1[tid] = a1 > 0.f ? a1 : 0.f;
  __syncthreads();
  if (tid < 64) {
    float a2 = mb2[tid];
    for (int k = 0; k < HID; ++k) a2 += z1[k] * M2[k * 64 + tid];
    z2[tid] = a2 > 0.f ? a2 : 0.f;
  }
  __syncthreads();
  if (tid < 2) {
    float a3 = mb3[tid];
    for (int k = 0; k < 64; ++k) a3 += z2[k] * M3[k * 2 + tid];
    out[g * 2 + tid] = a3;
  }
}

extern "C" void kernel_launch(void* const* d_in, const int* in_sizes, int n_in,
                              void* d_out, int out_size, void* d_ws, size_t ws_size,
                              hipStream_t stream) {
  const float* x   = (const float*)d_in[0];
  const int*   ei  = (const int*)d_in[1];
  const int*   bat = (const int*)d_in[2];
  const float* bst = (const float*)d_in[3];
  const float* W1 = (const float*)d_in[4];
  const float* as1 = (const float*)d_in[5];
  const float* ad1 = (const float*)d_in[6];
  const float* b1 = (const float*)d_in[7];
  const float* W2 = (const float*)d_in[8];
  const float* as2 = (const float*)d_in[9];
  const float* ad2 = (const float*)d_in[10];
  const float* b2 = (const float*)d_in[11];
  const float* W3 = (const float*)d_in[12];
  const float* as3 = (const float*)d_in[13];
  const float* ad3 = (const float*)d_in[14];
  const float* b3 = (const float*)d_in[15];
  const float* M1 = (const float*)d_in[16];
  const float* mb1 = (const float*)d_in[17];
  const float* M2 = (const float*)d_in[18];
  const float* mb2 = (const float*)d_in[19];
  const float* M3 = (const float*)d_in[20];
  const float* mb3 = (const float*)d_in[21];
  float* out = (float*)d_out;

  char* ws = (char*)d_ws;
  auto alloc = [&](size_t bytes) -> void* {
    void* p = (void*)ws;
    ws += (bytes + 255) & ~(size_t)255;
    return p;
  };
  float* h_buf  = (float*)alloc((size_t)NN * OUTC * 4);
  float* x_buf  = (float*)alloc((size_t)NN * HID * 4);
  float* e_src  = (float*)alloc((size_t)NN * 4 * 4);
  float* e_dst  = (float*)alloc((size_t)NN * 4 * 4);
  int*   deg    = (int*)alloc((size_t)NN * 4);
  int*   rowst  = (int*)alloc((size_t)(NN + 1) * 4);
  int*   cursor = (int*)alloc((size_t)NN * 4);
  int*   csr    = (int*)alloc((size_t)ET * 4);
  float* gsums  = (float*)alloc((size_t)NG * HID * 4);

  // CSR by destination
  hipMemsetAsync(deg, 0, (size_t)NN * 4, stream);
  hipMemsetAsync(gsums, 0, (size_t)NG * HID * 4, stream);
  k_hist<<<(ET + 255) / 256, 256, 0, stream>>>(ei, deg);
  k_scan<<<1, 1024, 0, stream>>>(deg, rowst, cursor);
  k_scatter<<<(ET + 255) / 256, 256, 0, stream>>>(ei, cursor, csr);

  dim3 ggrid(OUTC / 64, (NN + 63) / 64);
  dim3 agrid(NN / 2);   // NN even: every wave active, barrier is uniform
  // layer 1
  k_gemm_t<12, 12><<<ggrid, 256, 0, stream>>>(x, W1, h_buf);
  k_esd<<<NN, 128, 0, stream>>>(h_buf, as1, ad1, e_src, e_dst);
  k_agg<0><<<agrid, 256, 0, stream>>>(h_buf, e_src, e_dst, rowst, csr, b1, x_buf, bat, gsums);
  // layer 2
  k_gemm_t<128, 64><<<ggrid, 256, 0, stream>>>(x_buf, W2, h_buf);
  k_esd<<<NN, 128, 0, stream>>>(h_buf, as2, ad2, e_src, e_dst);
  k_agg<0><<<agrid, 256, 0, stream>>>(h_buf, e_src, e_dst, rowst, csr, b2, x_buf, bat, gsums);
  // layer 3 (pool fused via atomics into gsums)
  k_gemm_t<128, 64><<<ggrid, 256, 0, stream>>>(x_buf, W3, h_buf);
  k_esd<<<NN, 128, 0, stream>>>(h_buf, as3, ad3, e_src, e_dst);
  k_agg<1><<<agrid, 256, 0, stream>>>(h_buf, e_src, e_dst, rowst, csr, b3, x_buf, bat, gsums);
  // MLP head
  k_mlp<<<NG, 128, 0, stream>>>(gsums, bat, bst, M1, mb1, M2, mb2, M3, mb3, out);
}